// Round 6
// baseline (594.503 us; speedup 1.0000x reference)
//
#include <hip/hip_runtime.h>
#include <math.h>

#define BB 32
#define TS 1024
#define DD 2048
#define UU 1024

typedef _Float16 f16x8 __attribute__((ext_vector_type(8)));
typedef _Float16 f16x2 __attribute__((ext_vector_type(2)));
typedef __fp16 fp16x2 __attribute__((ext_vector_type(2)));
typedef float f32x4 __attribute__((ext_vector_type(4)));

union H8 { f16x8 v; f16x2 p[4]; };

static __device__ inline f16x2 pk(float a, float b) {
  fp16x2 r = __builtin_amdgcn_cvt_pkrtz(a, b);
  return __builtin_bit_cast(f16x2, r);
}

// tanh via hw exp2+rcp: exact at +-inf, ~1e-6 abs err, ~5 VALU ops
static __device__ inline float fast_tanh(float x) {
  float e = __builtin_amdgcn_exp2f(x * 2.885390081777927f);  // exp(2x)
  return 1.f - 2.f * __builtin_amdgcn_rcpf(1.f + e);
}

// async global->LDS, 16B/lane; LDS dest wave-uniform (HW adds lane*16).
static __device__ inline void gld16(const _Float16* g, _Float16* l) {
  __builtin_amdgcn_global_load_lds(
      (const __attribute__((address_space(1))) void*)g,
      (__attribute__((address_space(3))) void*)l, 16, 0, 0);
}

// ---------------------------------------------------------------------------
// zero all of d_out (qpb lives in context region, score in weights region;
// both are atomic targets). 96 blocks x 1024 = 98304 floats.
// ---------------------------------------------------------------------------
__global__ void zero_kernel(float* __restrict__ p) {
  p[blockIdx.x * 1024 + threadIdx.x] = 0.f;
}

// ---------------------------------------------------------------------------
// Kernel A: qpb[b][u] += partial of query@W2 (+b1+b2 once).
// Grid 128 = (u0 in 8 x 128u) x (dsl in 16 x 128d). W2 read exactly once.
// ---------------------------------------------------------------------------
__global__ __launch_bounds__(256) void qproj_kernel(
    const float* __restrict__ query, const float* __restrict__ W2,
    const float* __restrict__ b1, const float* __restrict__ b2,
    float* __restrict__ qpb) {
  __shared__ float qs[32][128];  // 16 KB
  const int u0 = (blockIdx.x & 7) * 128;
  const int dsl = blockIdx.x >> 3;   // 0..15
  const int d0 = dsl * 128;
  const int tid = threadIdx.x;
  const int ul = tid & 127, half = tid >> 7;

  for (int i = tid; i < 32 * 32; i += 256) {  // 1024 float4 = 16 KB
    int b = i >> 5, dq = i & 31;
    *(float4*)&qs[b][dq * 4] = *(const float4*)(query + b * DD + d0 + dq * 4);
  }
  __syncthreads();

  float acc[32];
#pragma unroll
  for (int b = 0; b < 32; ++b) acc[b] = 0.f;

  const float* wcol = W2 + (size_t)(d0 + half * 64) * UU + u0 + ul;
  for (int dd = 0; dd < 64; dd += 4) {
    float w0 = wcol[(size_t)(dd + 0) * UU];
    float w1 = wcol[(size_t)(dd + 1) * UU];
    float w2 = wcol[(size_t)(dd + 2) * UU];
    float w3 = wcol[(size_t)(dd + 3) * UU];
#pragma unroll
    for (int b = 0; b < 32; ++b) {
      float4 q4 = *(const float4*)&qs[b][half * 64 + dd];
      acc[b] += q4.x * w0 + q4.y * w1 + q4.z * w2 + q4.w * w3;
    }
  }

  const int u = u0 + ul;
  const float bias = (dsl == 0 && half == 0) ? (b1[u] + b2[u]) : 0.f;
#pragma unroll
  for (int b = 0; b < 32; ++b) atomicAdd(&qpb[b * UU + u], acc[b] + bias);
}

// ---------------------------------------------------------------------------
// Pre-pass 1: values fp32 -> packed fp16 MFMA image (proven in R5).
// Output image is LINEAR: vhp[((mt*32+kc)*1024 + khi*128 + row)*8 + klo]
//   = fp16(values[mt*128+row][kc*64 + khi*8 + klo]).
// ---------------------------------------------------------------------------
__global__ __launch_bounds__(256) void pack_values_kernel(
    const float* __restrict__ v, _Float16* __restrict__ vhp) {
  __shared__ _Float16 img[8192];  // 16 KB
  const int mTile = blockIdx.x >> 5;
  const int kc = blockIdx.x & 31;
  const int tid = threadIdx.x;

#pragma unroll
  for (int i = 0; i < 4; ++i) {
    int idx = i * 256 + tid;
    int row = idx >> 3, khi = idx & 7;
    const float* src = v + ((size_t)(mTile * 128 + row)) * DD + kc * 64 + khi * 8;
    float4 x = *(const float4*)src;
    float4 y = *(const float4*)(src + 4);
    H8 h;
    h.p[0] = pk(x.x, x.y); h.p[1] = pk(x.z, x.w);
    h.p[2] = pk(y.x, y.y); h.p[3] = pk(y.z, y.w);
    *(f16x8*)&img[(khi * 128 + (row ^ khi)) * 8] = h.v;
  }
  __syncthreads();

  _Float16* out = vhp + ((size_t)mTile * 32 + kc) * 8192;
#pragma unroll
  for (int i = 0; i < 4; ++i) {
    int p = i * 256 + tid;
    int khi = p >> 7, row = p & 127;
    *(f16x8*)(out + (size_t)p * 8) = *(const f16x8*)&img[(khi * 128 + (row ^ khi)) * 8];
  }
}

// ---------------------------------------------------------------------------
// Pre-pass 2: W1 -> packed fp16 image of W1^T (proven in R5).
// ---------------------------------------------------------------------------
__global__ __launch_bounds__(256) void pack_w1_kernel(
    const float* __restrict__ W1, _Float16* __restrict__ w1p) {
  __shared__ _Float16 img[8192];
  const int nTile = blockIdx.x >> 5;
  const int kc = blockIdx.x & 31;
  const int tid = threadIdx.x;

#pragma unroll
  for (int i = 0; i < 32; ++i) {
    int idx = i * 256 + tid;
    int ul = idx & 127, kl = idx >> 7;
    float x = W1[(size_t)(kc * 64 + kl) * UU + nTile * 128 + ul];
    int khi = kl >> 3, klo = kl & 7;
    img[(khi * 128 + (ul ^ khi)) * 8 + klo] = (_Float16)x;
  }
  __syncthreads();

  _Float16* out = w1p + ((size_t)nTile * 32 + kc) * 8192;
#pragma unroll
  for (int i = 0; i < 4; ++i) {
    int p = i * 256 + tid;
    int khi = p >> 7, row = p & 127;
    *(f16x8*)(out + (size_t)p * 8) = *(const f16x8*)&img[(khi * 128 + (row ^ khi)) * 8];
  }
}

// ---------------------------------------------------------------------------
// Kernel B (R5 rewrite): 256x256 tile, BK=64, 8 waves, 4-phase counted-vmcnt
// schedule (T3+T4). Per K-tile t (slot sl=t&1), 4 phases:
//   ph0: ds_read B[k0]+A[k0,m0-3] | stage A_k0(t+1)->sl^1 | bar|lgkm0|16 MFMA|bar
//   ph1: ds_read A[k0,m4-7]       | stage B_k0(t+1)       | bar|lgkm0|16 MFMA|vmcnt(4)|bar
//   ph2: ds_read B[k1]+A[k1,m0-3] | stage A_k1(t+1)       | bar|lgkm0|16 MFMA|bar
//   ph3: ds_read A[k1,m4-7]       | stage B_k1(t+1)       | bar|lgkm0|16 MFMA|vmcnt(4)|bar
// vmcnt ledger (2 gld16/chunk/wave): at each vmcnt(4) the <=4 loads left in
// flight are exactly the 2 chunks not needed for 2 more phases; the oldest 4
// (the chunks the next 2 phases read) are drained. Never vmcnt(0) in loop;
// epilogue tile 31 drains 4->0. LDS slot so=sl^1 was last read at t-1 and all
// its ds_reads completed before t-1's final barrier -> WAR-safe.
// ---------------------------------------------------------------------------
__global__ __launch_bounds__(512, 2) void score_gemm_p3_kernel(
    const _Float16* __restrict__ vhp, const _Float16* __restrict__ w1p,
    const float* __restrict__ qpb, const float* __restrict__ V,
    float* __restrict__ score) {
  __shared__ _Float16 aS[2][16384];  // [slot][mhalf2][koct8][row128][klo8] 64 KB
  __shared__ _Float16 bS[2][16384];  // 64 KB

  const int tid = threadIdx.x;
  const int lane = tid & 63, wave = tid >> 6;

  // XCD-aware swizzle (512 blocks = 8 XCDs x 64, bijective)
  const int swz = (blockIdx.x & 7) * 64 + (blockIdx.x >> 3);
  const int mb = swz >> 2;   // 0..127 (256-row M tile)
  const int nb = swz & 3;    // 0..3   (256-col N tile)

  const int wr = wave >> 2;  // 0..1: M half (128 rows)
  const int wc = wave & 3;   // 0..3: N quarter (64 cols)
  const int quad = lane >> 4, c16 = lane & 15;

  const _Float16* gA0 = vhp + ((size_t)(2 * mb + 0) * 32) * 8192 + lane * 8;
  const _Float16* gA1 = vhp + ((size_t)(2 * mb + 1) * 32) * 8192 + lane * 8;
  const _Float16* gB0 = w1p + ((size_t)(2 * nb + 0) * 32) * 8192 + lane * 8;
  const _Float16* gB1 = w1p + ((size_t)(2 * nb + 1) * 32) * 8192 + lane * 8;

  f32x4 acc[8][4];
#pragma unroll
  for (int mi = 0; mi < 8; ++mi)
#pragma unroll
    for (int ni = 0; ni < 4; ++ni) acc[mi][ni] = (f32x4)0.f;

  // one 16-KB chunk = {A or B} x k-half; 2 gld16/wave (waves cover 8 KB each
  // per mhalf/nhalf region; linear copy, LDS layout == image layout).
  auto STAGE_A = [&](int kt, int sl, int kh) {
    gld16(gA0 + (size_t)kt * 8192 + kh * 4096 + wave * 512,
          &aS[sl][0 * 8192 + kh * 4096 + wave * 512]);
    gld16(gA1 + (size_t)kt * 8192 + kh * 4096 + wave * 512,
          &aS[sl][1 * 8192 + kh * 4096 + wave * 512]);
  };
  auto STAGE_B = [&](int kt, int sl, int kh) {
    gld16(gB0 + (size_t)kt * 8192 + kh * 4096 + wave * 512,
          &bS[sl][0 * 8192 + kh * 4096 + wave * 512]);
    gld16(gB1 + (size_t)kt * 8192 + kh * 4096 + wave * 512,
          &bS[sl][1 * 8192 + kh * 4096 + wave * 512]);
  };

  // epilogue params FIRST so their vmem loads are oldest (drained at first wait)
  const int b = mb >> 2;
  const int nBase = nb * 256;
  float qv[4], vv[4];
#pragma unroll
  for (int ni = 0; ni < 4; ++ni) {
    int ug = nBase + wc * 64 + ni * 16 + c16;
    qv[ni] = qpb[b * UU + ug];
    vv[ni] = V[ug];
  }

  // prologue: stage tile 0 in need-order, wait for first two chunks
  STAGE_A(0, 0, 0); STAGE_B(0, 0, 0); STAGE_A(0, 0, 1); STAGE_B(0, 0, 1);
  asm volatile("s_waitcnt vmcnt(4)" ::: "memory");
  __builtin_amdgcn_s_barrier();
  __builtin_amdgcn_sched_barrier(0);

  const int aBase = wr * 8192 + c16 * 8;
  const int bBase = (wc >> 1) * 8192 + ((wc & 1) * 64 + c16) * 8;

  f16x8 bf[4];
  auto DS_B = [&](int sl, int hk) {
#pragma unroll
    for (int ni = 0; ni < 4; ++ni)
      bf[ni] = *(const f16x8*)&bS[sl][bBase + (hk * 4 + quad) * 1024 + ni * 128];
  };
  auto DS_A = [&](int sl, int hk, int g, f16x8* af) {
#pragma unroll
    for (int mi = 0; mi < 4; ++mi)
      af[mi] = *(const f16x8*)&aS[sl][aBase + (hk * 4 + quad) * 1024 + (g * 4 + mi) * 128];
  };
  auto MFMA16 = [&](int g, f16x8* af) {
    __builtin_amdgcn_s_setprio(1);
#pragma unroll
    for (int mi = 0; mi < 4; ++mi)
#pragma unroll
      for (int ni = 0; ni < 4; ++ni)
        acc[g * 4 + mi][ni] = __builtin_amdgcn_mfma_f32_16x16x32_f16(
            af[mi], bf[ni], acc[g * 4 + mi][ni], 0, 0, 0);
    __builtin_amdgcn_s_setprio(0);
  };
#define LGKM0_FENCE                                    \
  asm volatile("s_waitcnt lgkmcnt(0)" ::: "memory");   \
  __builtin_amdgcn_sched_barrier(0)

  for (int t = 0; t < 31; ++t) {
    const int sl = t & 1, so = sl ^ 1;
    {  // ph0: kslice0, m0-3
      f16x8 af[4];
      DS_B(sl, 0); DS_A(sl, 0, 0, af);
      STAGE_A(t + 1, so, 0);
      __builtin_amdgcn_s_barrier();
      LGKM0_FENCE;
      MFMA16(0, af);
      __builtin_amdgcn_s_barrier();
    }
    {  // ph1: kslice0, m4-7
      f16x8 af[4];
      DS_A(sl, 0, 1, af);
      STAGE_B(t + 1, so, 0);
      __builtin_amdgcn_s_barrier();
      LGKM0_FENCE;
      MFMA16(1, af);
      asm volatile("s_waitcnt vmcnt(4)" ::: "memory");
      __builtin_amdgcn_s_barrier();
      __builtin_amdgcn_sched_barrier(0);
    }
    {  // ph2: kslice1, m0-3
      f16x8 af[4];
      DS_B(sl, 1); DS_A(sl, 1, 0, af);
      STAGE_A(t + 1, so, 1);
      __builtin_amdgcn_s_barrier();
      LGKM0_FENCE;
      MFMA16(0, af);
      __builtin_amdgcn_s_barrier();
    }
    {  // ph3: kslice1, m4-7
      f16x8 af[4];
      DS_A(sl, 1, 1, af);
      STAGE_B(t + 1, so, 1);
      __builtin_amdgcn_s_barrier();
      LGKM0_FENCE;
      MFMA16(1, af);
      asm volatile("s_waitcnt vmcnt(4)" ::: "memory");
      __builtin_amdgcn_s_barrier();
      __builtin_amdgcn_sched_barrier(0);
    }
  }
  {  // epilogue: t = 31, sl = 1; no stages; drain 4 -> 0
    f16x8 af[4];
    DS_B(1, 0); DS_A(1, 0, 0, af);
    __builtin_amdgcn_s_barrier();
    LGKM0_FENCE;
    MFMA16(0, af);
    __builtin_amdgcn_s_barrier();

    DS_A(1, 0, 1, af);
    __builtin_amdgcn_s_barrier();
    LGKM0_FENCE;
    MFMA16(1, af);
    asm volatile("s_waitcnt vmcnt(0)" ::: "memory");
    __builtin_amdgcn_s_barrier();
    __builtin_amdgcn_sched_barrier(0);

    DS_B(1, 1); DS_A(1, 1, 0, af);
    __builtin_amdgcn_s_barrier();
    LGKM0_FENCE;
    MFMA16(0, af);
    __builtin_amdgcn_s_barrier();

    DS_A(1, 1, 1, af);
    __builtin_amdgcn_s_barrier();
    LGKM0_FENCE;
    MFMA16(1, af);
  }
#undef LGKM0_FENCE

#pragma unroll
  for (int mi = 0; mi < 8; ++mi) {
#pragma unroll
    for (int reg = 0; reg < 4; ++reg) {
      float p = fast_tanh(acc[mi][0][reg] + qv[0]) * vv[0] +
                fast_tanh(acc[mi][1][reg] + qv[1]) * vv[1] +
                fast_tanh(acc[mi][2][reg] + qv[2]) * vv[2] +
                fast_tanh(acc[mi][3][reg] + qv[3]) * vv[3];
      p += __shfl_xor(p, 1, 64);
      p += __shfl_xor(p, 2, 64);
      p += __shfl_xor(p, 4, 64);
      p += __shfl_xor(p, 8, 64);
      if (c16 == 0) {
        int mrow = mb * 256 + wr * 128 + mi * 16 + quad * 4 + reg;
        atomicAdd(&score[mrow], p);
      }
    }
  }
}

// ---------------------------------------------------------------------------
// Kernel B fallback (small ws): fp32-in, cvt per tile (R3 core, fast_tanh).
// ---------------------------------------------------------------------------
__global__ __launch_bounds__(256) void score_gemm_kernel(
    const float* __restrict__ values, const float* __restrict__ W1,
    const float* __restrict__ qpb, const float* __restrict__ V,
    float* __restrict__ score) {
  __shared__ _Float16 aS[4 * 128 * 8];
  __shared__ _Float16 bS[4 * 128 * 8];

  const int tid = threadIdx.x;
  const int mBase = (blockIdx.x >> 3) * 128;
  const int nBase = (blockIdx.x & 7) * 128;

  const int am = tid >> 1;
  const int akh = (tid & 1) * 16;
  const float* aG = values + (size_t)(mBase + am) * DD + akh;
  const int aOff0 = (((tid & 1) * 2) * 128 + am) * 8;
  const int bu2 = (tid & 63) * 2;
  const int bkq = tid >> 6;
  const float* bG = W1 + (size_t)(bkq * 8) * UU + nBase + bu2;
  const int bOff0 = (bkq * 128 + bu2) * 8;

  const int lane = tid & 63;
  const int wave = tid >> 6;
  const int wm = (wave & 1) * 64;
  const int wn = (wave >> 1) * 64;
  const int quad = lane >> 4;
  const int c16 = lane & 15;

  f32x4 acc[4][4];
#pragma unroll
  for (int mi = 0; mi < 4; ++mi)
#pragma unroll
    for (int ni = 0; ni < 4; ++ni) acc[mi][ni] = (f32x4)0.f;

  for (int k0 = 0; k0 < DD; k0 += 32) {
    float4 a0 = *(const float4*)(aG + k0 + 0);
    float4 a1 = *(const float4*)(aG + k0 + 4);
    float4 a2 = *(const float4*)(aG + k0 + 8);
    float4 a3 = *(const float4*)(aG + k0 + 12);
    const float* bRow = bG + (size_t)k0 * UU;
    float2 g0 = *(const float2*)(bRow + 0 * UU);
    float2 g1 = *(const float2*)(bRow + 1 * UU);
    float2 g2 = *(const float2*)(bRow + 2 * UU);
    float2 g3 = *(const float2*)(bRow + 3 * UU);
    float2 g4 = *(const float2*)(bRow + 4 * UU);
    float2 g5 = *(const float2*)(bRow + 5 * UU);
    float2 g6 = *(const float2*)(bRow + 6 * UU);
    float2 g7 = *(const float2*)(bRow + 7 * UU);

    __syncthreads();

    H8 ha0, ha1, hb0, hb1;
    ha0.p[0] = pk(a0.x, a0.y); ha0.p[1] = pk(a0.z, a0.w);
    ha0.p[2] = pk(a1.x, a1.y); ha0.p[3] = pk(a1.z, a1.w);
    ha1.p[0] = pk(a2.x, a2.y); ha1.p[1] = pk(a2.z, a2.w);
    ha1.p[2] = pk(a3.x, a3.y); ha1.p[3] = pk(a3.z, a3.w);
    *(f16x8*)&aS[aOff0] = ha0.v;
    *(f16x8*)&aS[aOff0 + 1024] = ha1.v;

    hb0.p[0] = pk(g0.x, g1.x); hb0.p[1] = pk(g2.x, g3.x);
    hb0.p[2] = pk(g4.x, g5.x); hb0.p[3] = pk(g6.x, g7.x);
    hb1.p[0] = pk(g0.y, g1.y); hb1.p[1] = pk(g2.y, g3.y);
    hb1.p[2] = pk(g4.y, g5.y); hb1.p[3] = pk(g6.y, g7.y);
    *(f16x8*)&bS[bOff0] = hb0.v;
    *(f16x8*)&bS[bOff0 + 8] = hb1.v;

    __syncthreads();

    f16x8 af[4], bf[4];
#pragma unroll
    for (int i = 0; i < 4; ++i) {
      af[i] = *(const f16x8*)&aS[(quad * 128 + wm + i * 16 + c16) * 8];
      bf[i] = *(const f16x8*)&bS[(quad * 128 + wn + i * 16 + c16) * 8];
    }
#pragma unroll
    for (int mi = 0; mi < 4; ++mi)
#pragma unroll
      for (int ni = 0; ni < 4; ++ni)
        acc[mi][ni] = __builtin_amdgcn_mfma_f32_16x16x32_f16(
            af[mi], bf[ni], acc[mi][ni], 0, 0, 0);
  }

  const int b = mBase >> 10;
  float qv[4], vv[4];
#pragma unroll
  for (int ni = 0; ni < 4; ++ni) {
    int ug = nBase + wn + ni * 16 + c16;
    qv[ni] = qpb[b * UU + ug];
    vv[ni] = V[ug];
  }
#pragma unroll
  for (int mi = 0; mi < 4; ++mi) {
#pragma unroll
    for (int reg = 0; reg < 4; ++reg) {
      float p = fast_tanh(acc[mi][0][reg] + qv[0]) * vv[0] +
                fast_tanh(acc[mi][1][reg] + qv[1]) * vv[1] +
                fast_tanh(acc[mi][2][reg] + qv[2]) * vv[2] +
                fast_tanh(acc[mi][3][reg] + qv[3]) * vv[3];
      p += __shfl_xor(p, 1, 64);
      p += __shfl_xor(p, 2, 64);
      p += __shfl_xor(p, 4, 64);
      p += __shfl_xor(p, 8, 64);
      if (c16 == 0) {
        int mrow = mBase + wm + mi * 16 + quad * 4 + reg;
        atomicAdd(&score[mrow], p);
      }
    }
  }
}

// ---------------------------------------------------------------------------
// Kernel C: softmax over T per batch, in-place. 1024 threads, 1 elem each,
// shfl reductions.
// ---------------------------------------------------------------------------
__global__ __launch_bounds__(1024) void softmax_kernel(float* __restrict__ sw) {
  __shared__ float red[16];
  const int b = blockIdx.x;
  const int tid = threadIdx.x;
  const int wid = tid >> 6, lane = tid & 63;
  float* s = sw + b * TS;

  const float v = s[tid];

  float m = v;
#pragma unroll
  for (int off = 32; off > 0; off >>= 1) m = fmaxf(m, __shfl_xor(m, off, 64));
  if (lane == 0) red[wid] = m;
  __syncthreads();
  float mm = red[0];
#pragma unroll
  for (int i = 1; i < 16; ++i) mm = fmaxf(mm, red[i]);
  __syncthreads();

  const float e = expf(v - mm);
  float sum = e;
#pragma unroll
  for (int off = 32; off > 0; off >>= 1) sum += __shfl_xor(sum, off, 64);
  if (lane == 0) red[wid] = sum;
  __syncthreads();
  float tot = 0.f;
#pragma unroll
  for (int i = 0; i < 16; ++i) tot += red[i];

  s[tid] = e * (1.f / tot);
}

// ---------------------------------------------------------------------------
// Kernel D (fp16 image): context[b][d] = sum_t w[b][t] * v[b][t][d].
// Grid 1024 = b(32) x kc(32, 64-d chunks). Block 256 = 4 waves.
// ---------------------------------------------------------------------------
__global__ __launch_bounds__(256) void context_p_kernel(
    const _Float16* __restrict__ vhp, const float* __restrict__ weights,
    float* __restrict__ context) {
  __shared__ float wl[TS];
  const int b = blockIdx.x >> 5;
  const int kc = blockIdx.x & 31;
  const int tid = threadIdx.x;
  const int lane = tid & 63, wave = tid >> 6;

  for (int i = tid; i < TS; i += 256) wl[i] = weights[b * TS + i];
  __syncthreads();

  const int khiA = wave;
  const int khiB = wave + 4;

  float acc0[8], acc1[8];
#pragma unroll
  for (int j = 0; j < 8; ++j) { acc0[j] = 0.f; acc1[j] = 0.f; }

  for (int mt8 = 0; mt8 < 8; ++mt8) {
    const _Float16* base = vhp + ((size_t)(b * 8 + mt8) * 32 + kc) * 8192;
    const float* wrow = &wl[mt8 * 128];
#pragma unroll
    for (int half = 0; half < 2; ++half) {
      const int row = half * 64 + lane;
      const float wt = wrow[row];
      f16x8 vA = *(const f16x8*)&base[(khiA * 128 + row) * 8];
      f16x8 vB = *(const f16x8*)&base[(khiB * 128 + row) * 8];
#pragma unroll
      for (int j = 0; j < 8; ++j) {
        acc0[j] += wt * (float)vA[j];
        acc1[j] += wt * (float)vB[j];
      }
    }
  }

#pragma unroll
  for (int j = 0; j < 8; ++j) {
    float a = acc0[j], c = acc1[j];
#pragma unroll
    for (int off = 1; off < 64; off <<= 1) {
      a += __shfl_xor(a, off, 64);
      c += __shfl_xor(c, off, 64);
    }
    acc0[j] = a; acc1[j] = c;
  }

  if (lane == 0) {
    float* dst = context + b * DD + kc * 64;
#pragma unroll
    for (int j = 0; j < 8; ++j) {
      dst[khiA * 8 + j] = acc0[j];
      dst[khiB * 8 + j] = acc1[j];
    }
  }
}

// ---------------------------------------------------------------------------
// Kernel D fallback (small ws): fp32 values read.
// ---------------------------------------------------------------------------
__global__ __launch_bounds__(1024) void context_kernel(
    const float* __restrict__ values, const float* __restrict__ weights,
    float* __restrict__ context) {
  __shared__ float wl[TS];
  __shared__ float4 part[15][64];
  const int b = blockIdx.x >> 3;
  const int d0 = (blockIdx.x & 7) * 256;
  const int tid = threadIdx.x;
  const int slice = tid >> 6, dl = tid & 63;

  wl[tid] = weights[b * TS + tid];
  __syncthreads();

  const float* vb = values + ((size_t)b * TS + slice * 64) * DD + d0 + dl * 4;
  float4 acc = {0.f, 0.f, 0.f, 0.f};
#pragma unroll 8
  for (int t = 0; t < 64; ++t) {
    float w = wl[slice * 64 + t];
    float4 v4 = *(const float4*)(vb + (size_t)t * DD);
    acc.x += w * v4.x; acc.y += w * v4.y;
    acc.z += w * v4.z; acc.w += w * v4.w;
  }

  if (slice) part[slice - 1][dl] = acc;
  __syncthreads();
  if (slice == 0) {
#pragma unroll
    for (int i = 0; i < 15; ++i) {
      float4 p = part[i][dl];
      acc.x += p.x; acc.y += p.y; acc.z += p.z; acc.w += p.w;
    }
    *(float4*)(context + b * DD + d0 + dl * 4) = acc;
  }
}

// ---------------------------------------------------------------------------
extern "C" void kernel_launch(void* const* d_in, const int* in_sizes, int n_in,
                              void* d_out, int out_size, void* d_ws, size_t ws_size,
                              hipStream_t stream) {
  const float* query  = (const float*)d_in[0];
  const float* values = (const float*)d_in[1];
  const float* W1     = (const float*)d_in[2];
  const float* b1     = (const float*)d_in[3];
  const float* W2     = (const float*)d_in[4];
  const float* b2     = (const float*)d_in[5];
  const float* V      = (const float*)d_in[6];
  // d_in[7] = bv cancels in softmax; unused.

  float* out = (float*)d_out;
  float* context = out;            // B*D (output 0)
  float* weights = out + BB * DD;  // B*T (output 1)

  float* qpb   = context;  // atomic target; overwritten by context kernel later
  float* score = weights;  // atomic target; softmax in-place

  const size_t need = (size_t)BB * TS * DD * 2 + (size_t)DD * UU * 2;
  const bool big_ws = ws_size >= need;

  zero_kernel<<<96, 1024, 0, stream>>>(out);  // zeros qpb + score regions
  qproj_kernel<<<128, 256, 0, stream>>>(query, W2, b1, b2, qpb);

  if (big_ws) {
    _Float16* vhp = (_Float16*)d_ws;
    _Float16* w1p = vhp + (size_t)BB * TS * DD;
    pack_values_kernel<<<256 * 32, 256, 0, stream>>>(values, vhp);
    pack_w1_kernel<<<8 * 32, 256, 0, stream>>>(W1, w1p);
    score_gemm_p3_kernel<<<(BB * TS / 256) * (UU / 256), 512, 0, stream>>>(
        vhp, w1p, qpb, V, score);
    softmax_kernel<<<BB, 1024, 0, stream>>>(score);
    context_p_kernel<<<BB * 32, 256, 0, stream>>>(vhp, weights, context);
  } else {
    score_gemm_kernel<<<(BB * TS / 128) * (UU / 128), 256, 0, stream>>>(
        values, W1, qpb, V, score);
    softmax_kernel<<<BB, 1024, 0, stream>>>(score);
    context_kernel<<<BB * 8, 1024, 0, stream>>>(values, weights, context);
  }
}

// Round 7
// 593.790 us; speedup vs baseline: 1.0012x; 1.0012x over previous
//
#include <hip/hip_runtime.h>
#include <math.h>

#define BB 32
#define TS 1024
#define DD 2048
#define UU 1024

typedef _Float16 f16x8 __attribute__((ext_vector_type(8)));
typedef _Float16 f16x2 __attribute__((ext_vector_type(2)));
typedef __fp16 fp16x2 __attribute__((ext_vector_type(2)));
typedef float f32x4 __attribute__((ext_vector_type(4)));

union H8 { f16x8 v; f16x2 p[4]; };

static __device__ inline f16x2 pk(float a, float b) {
  fp16x2 r = __builtin_amdgcn_cvt_pkrtz(a, b);
  return __builtin_bit_cast(f16x2, r);
}

// tanh via hw exp2+rcp: exact at +-inf, ~1e-6 abs err, ~5 VALU ops
static __device__ inline float fast_tanh(float x) {
  float e = __builtin_amdgcn_exp2f(x * 2.885390081777927f);  // exp(2x)
  return 1.f - 2.f * __builtin_amdgcn_rcpf(1.f + e);
}

// async global->LDS, 16B/lane; LDS dest wave-uniform (HW adds lane*16).
static __device__ inline void gld16(const _Float16* g, _Float16* l) {
  __builtin_amdgcn_global_load_lds(
      (const __attribute__((address_space(1))) void*)g,
      (__attribute__((address_space(3))) void*)l, 16, 0, 0);
}

// ---------------------------------------------------------------------------
// zero all of d_out (qpb lives in context region, score in weights region;
// both are atomic targets). 96 blocks x 1024 = 98304 floats.
// ---------------------------------------------------------------------------
__global__ void zero_kernel(float* __restrict__ p) {
  p[blockIdx.x * 1024 + threadIdx.x] = 0.f;
}

// ---------------------------------------------------------------------------
// Kernel A: qpb[b][u] += partial of query@W2 (+b1+b2 once).
// Grid 128 = (u0 in 8 x 128u) x (dsl in 16 x 128d). W2 read exactly once.
// ---------------------------------------------------------------------------
__global__ __launch_bounds__(256) void qproj_kernel(
    const float* __restrict__ query, const float* __restrict__ W2,
    const float* __restrict__ b1, const float* __restrict__ b2,
    float* __restrict__ qpb) {
  __shared__ float qs[32][128];  // 16 KB
  const int u0 = (blockIdx.x & 7) * 128;
  const int dsl = blockIdx.x >> 3;   // 0..15
  const int d0 = dsl * 128;
  const int tid = threadIdx.x;
  const int ul = tid & 127, half = tid >> 7;

  for (int i = tid; i < 32 * 32; i += 256) {  // 1024 float4 = 16 KB
    int b = i >> 5, dq = i & 31;
    *(float4*)&qs[b][dq * 4] = *(const float4*)(query + b * DD + d0 + dq * 4);
  }
  __syncthreads();

  float acc[32];
#pragma unroll
  for (int b = 0; b < 32; ++b) acc[b] = 0.f;

  const float* wcol = W2 + (size_t)(d0 + half * 64) * UU + u0 + ul;
  for (int dd = 0; dd < 64; dd += 4) {
    float w0 = wcol[(size_t)(dd + 0) * UU];
    float w1 = wcol[(size_t)(dd + 1) * UU];
    float w2 = wcol[(size_t)(dd + 2) * UU];
    float w3 = wcol[(size_t)(dd + 3) * UU];
#pragma unroll
    for (int b = 0; b < 32; ++b) {
      float4 q4 = *(const float4*)&qs[b][half * 64 + dd];
      acc[b] += q4.x * w0 + q4.y * w1 + q4.z * w2 + q4.w * w3;
    }
  }

  const int u = u0 + ul;
  const float bias = (dsl == 0 && half == 0) ? (b1[u] + b2[u]) : 0.f;
#pragma unroll
  for (int b = 0; b < 32; ++b) atomicAdd(&qpb[b * UU + u], acc[b] + bias);
}

// ---------------------------------------------------------------------------
// Pre-pass 1: values fp32 -> packed fp16 MFMA image (proven in R5).
// Output image is LINEAR: vhp[((mt*32+kc)*1024 + khi*128 + row)*8 + klo]
//   = fp16(values[mt*128+row][kc*64 + khi*8 + klo]).
// ---------------------------------------------------------------------------
__global__ __launch_bounds__(256) void pack_values_kernel(
    const float* __restrict__ v, _Float16* __restrict__ vhp) {
  __shared__ _Float16 img[8192];  // 16 KB
  const int mTile = blockIdx.x >> 5;
  const int kc = blockIdx.x & 31;
  const int tid = threadIdx.x;

#pragma unroll
  for (int i = 0; i < 4; ++i) {
    int idx = i * 256 + tid;
    int row = idx >> 3, khi = idx & 7;
    const float* src = v + ((size_t)(mTile * 128 + row)) * DD + kc * 64 + khi * 8;
    float4 x = *(const float4*)src;
    float4 y = *(const float4*)(src + 4);
    H8 h;
    h.p[0] = pk(x.x, x.y); h.p[1] = pk(x.z, x.w);
    h.p[2] = pk(y.x, y.y); h.p[3] = pk(y.z, y.w);
    *(f16x8*)&img[(khi * 128 + (row ^ khi)) * 8] = h.v;
  }
  __syncthreads();

  _Float16* out = vhp + ((size_t)mTile * 32 + kc) * 8192;
#pragma unroll
  for (int i = 0; i < 4; ++i) {
    int p = i * 256 + tid;
    int khi = p >> 7, row = p & 127;
    *(f16x8*)(out + (size_t)p * 8) = *(const f16x8*)&img[(khi * 128 + (row ^ khi)) * 8];
  }
}

// ---------------------------------------------------------------------------
// Pre-pass 2: W1 -> packed fp16 image of W1^T (proven in R5).
// ---------------------------------------------------------------------------
__global__ __launch_bounds__(256) void pack_w1_kernel(
    const float* __restrict__ W1, _Float16* __restrict__ w1p) {
  __shared__ _Float16 img[8192];
  const int nTile = blockIdx.x >> 5;
  const int kc = blockIdx.x & 31;
  const int tid = threadIdx.x;

#pragma unroll
  for (int i = 0; i < 32; ++i) {
    int idx = i * 256 + tid;
    int ul = idx & 127, kl = idx >> 7;
    float x = W1[(size_t)(kc * 64 + kl) * UU + nTile * 128 + ul];
    int khi = kl >> 3, klo = kl & 7;
    img[(khi * 128 + (ul ^ khi)) * 8 + klo] = (_Float16)x;
  }
  __syncthreads();

  _Float16* out = w1p + ((size_t)nTile * 32 + kc) * 8192;
#pragma unroll
  for (int i = 0; i < 4; ++i) {
    int p = i * 256 + tid;
    int khi = p >> 7, row = p & 127;
    *(f16x8*)(out + (size_t)p * 8) = *(const f16x8*)&img[(khi * 128 + (row ^ khi)) * 8];
  }
}

// ---------------------------------------------------------------------------
// Kernel B (R6 -> R7): same 4-phase counted-vmcnt skeleton as R6 (verified
// passing), with ALL sched_barrier(0) and blanket lgkmcnt(0) fences REMOVED.
// Rationale: ds_read->MFMA deps are compiler-tracked (counted lgkmcnt emitted
// automatically, finer than a blanket 0); WAR on LDS slot reuse is ordered by
// the phase barriers (a wave at a barrier has consumed its MFMAs => its
// ds_reads completed); the gld16->LDS RAW is fenced by the vmcnt asm whose
// ::: "memory" clobber also blocks compile-time hoisting of next-tile
// ds_reads. m141 datum: full order-pinning costs ~40%.
// vmcnt ledger unchanged from R6: vmcnt(4) at ph1/ph3 ends; at each wait the
// <=4 loads left in flight are the 2 chunks not needed for 2 more phases.
// ---------------------------------------------------------------------------
__global__ __launch_bounds__(512, 2) void score_gemm_p4_kernel(
    const _Float16* __restrict__ vhp, const _Float16* __restrict__ w1p,
    const float* __restrict__ qpb, const float* __restrict__ V,
    float* __restrict__ score) {
  __shared__ _Float16 aS[2][16384];  // [slot][mhalf2][koct8][row128][klo8] 64 KB
  __shared__ _Float16 bS[2][16384];  // 64 KB

  const int tid = threadIdx.x;
  const int lane = tid & 63, wave = tid >> 6;

  // XCD-aware swizzle (512 blocks = 8 XCDs x 64, bijective); the 4 nb-blocks
  // of each mb land on one XCD -> A panel served from that XCD's L2.
  const int swz = (blockIdx.x & 7) * 64 + (blockIdx.x >> 3);
  const int mb = swz >> 2;   // 0..127 (256-row M tile)
  const int nb = swz & 3;    // 0..3   (256-col N tile)

  const int wr = wave >> 2;  // 0..1: M half (128 rows)
  const int wc = wave & 3;   // 0..3: N quarter (64 cols)
  const int quad = lane >> 4, c16 = lane & 15;

  const _Float16* gA0 = vhp + ((size_t)(2 * mb + 0) * 32) * 8192 + lane * 8;
  const _Float16* gA1 = vhp + ((size_t)(2 * mb + 1) * 32) * 8192 + lane * 8;
  const _Float16* gB0 = w1p + ((size_t)(2 * nb + 0) * 32) * 8192 + lane * 8;
  const _Float16* gB1 = w1p + ((size_t)(2 * nb + 1) * 32) * 8192 + lane * 8;

  f32x4 acc[8][4];
#pragma unroll
  for (int mi = 0; mi < 8; ++mi)
#pragma unroll
    for (int ni = 0; ni < 4; ++ni) acc[mi][ni] = (f32x4)0.f;

  // one 16-KB chunk = {A or B} x k-half; 2 gld16/wave.
  auto STAGE_A = [&](int kt, int sl, int kh) {
    gld16(gA0 + (size_t)kt * 8192 + kh * 4096 + wave * 512,
          &aS[sl][0 * 8192 + kh * 4096 + wave * 512]);
    gld16(gA1 + (size_t)kt * 8192 + kh * 4096 + wave * 512,
          &aS[sl][1 * 8192 + kh * 4096 + wave * 512]);
  };
  auto STAGE_B = [&](int kt, int sl, int kh) {
    gld16(gB0 + (size_t)kt * 8192 + kh * 4096 + wave * 512,
          &bS[sl][0 * 8192 + kh * 4096 + wave * 512]);
    gld16(gB1 + (size_t)kt * 8192 + kh * 4096 + wave * 512,
          &bS[sl][1 * 8192 + kh * 4096 + wave * 512]);
  };

  // epilogue params FIRST so their vmem loads are oldest (drained at first wait)
  const int b = mb >> 2;
  const int nBase = nb * 256;
  float qv[4], vv[4];
#pragma unroll
  for (int ni = 0; ni < 4; ++ni) {
    int ug = nBase + wc * 64 + ni * 16 + c16;
    qv[ni] = qpb[b * UU + ug];
    vv[ni] = V[ug];
  }

  // prologue: stage tile 0 in need-order, wait for first two chunks
  STAGE_A(0, 0, 0); STAGE_B(0, 0, 0); STAGE_A(0, 0, 1); STAGE_B(0, 0, 1);
  asm volatile("s_waitcnt vmcnt(4)" ::: "memory");
  __builtin_amdgcn_s_barrier();

  const int aBase = wr * 8192 + c16 * 8;
  const int bBase = (wc >> 1) * 8192 + ((wc & 1) * 64 + c16) * 8;

  f16x8 bf[4];
  auto DS_B = [&](int sl, int hk) {
#pragma unroll
    for (int ni = 0; ni < 4; ++ni)
      bf[ni] = *(const f16x8*)&bS[sl][bBase + (hk * 4 + quad) * 1024 + ni * 128];
  };
  auto DS_A = [&](int sl, int hk, int g, f16x8* af) {
#pragma unroll
    for (int mi = 0; mi < 4; ++mi)
      af[mi] = *(const f16x8*)&aS[sl][aBase + (hk * 4 + quad) * 1024 + (g * 4 + mi) * 128];
  };
  auto MFMA16 = [&](int g, f16x8* af) {
    __builtin_amdgcn_s_setprio(1);
#pragma unroll
    for (int mi = 0; mi < 4; ++mi)
#pragma unroll
      for (int ni = 0; ni < 4; ++ni)
        acc[g * 4 + mi][ni] = __builtin_amdgcn_mfma_f32_16x16x32_f16(
            af[mi], bf[ni], acc[g * 4 + mi][ni], 0, 0, 0);
    __builtin_amdgcn_s_setprio(0);
  };

  for (int t = 0; t < 31; ++t) {
    const int sl = t & 1, so = sl ^ 1;
    {  // ph0: kslice0, m0-3
      f16x8 af[4];
      DS_B(sl, 0); DS_A(sl, 0, 0, af);
      STAGE_A(t + 1, so, 0);
      __builtin_amdgcn_s_barrier();
      MFMA16(0, af);
      __builtin_amdgcn_s_barrier();
    }
    {  // ph1: kslice0, m4-7
      f16x8 af[4];
      DS_A(sl, 0, 1, af);
      STAGE_B(t + 1, so, 0);
      __builtin_amdgcn_s_barrier();
      MFMA16(1, af);
      asm volatile("s_waitcnt vmcnt(4)" ::: "memory");
      __builtin_amdgcn_s_barrier();
    }
    {  // ph2: kslice1, m0-3
      f16x8 af[4];
      DS_B(sl, 1); DS_A(sl, 1, 0, af);
      STAGE_A(t + 1, so, 1);
      __builtin_amdgcn_s_barrier();
      MFMA16(0, af);
      __builtin_amdgcn_s_barrier();
    }
    {  // ph3: kslice1, m4-7
      f16x8 af[4];
      DS_A(sl, 1, 1, af);
      STAGE_B(t + 1, so, 1);
      __builtin_amdgcn_s_barrier();
      MFMA16(1, af);
      asm volatile("s_waitcnt vmcnt(4)" ::: "memory");
      __builtin_amdgcn_s_barrier();
    }
  }
  {  // epilogue: t = 31, sl = 1; no stages; drain 4 -> 0
    f16x8 af[4];
    DS_B(1, 0); DS_A(1, 0, 0, af);
    __builtin_amdgcn_s_barrier();
    MFMA16(0, af);
    __builtin_amdgcn_s_barrier();

    DS_A(1, 0, 1, af);
    __builtin_amdgcn_s_barrier();
    MFMA16(1, af);
    asm volatile("s_waitcnt vmcnt(0)" ::: "memory");
    __builtin_amdgcn_s_barrier();

    DS_B(1, 1); DS_A(1, 1, 0, af);
    __builtin_amdgcn_s_barrier();
    MFMA16(0, af);
    __builtin_amdgcn_s_barrier();

    DS_A(1, 1, 1, af);
    __builtin_amdgcn_s_barrier();
    MFMA16(1, af);
  }

#pragma unroll
  for (int mi = 0; mi < 8; ++mi) {
#pragma unroll
    for (int reg = 0; reg < 4; ++reg) {
      float p = fast_tanh(acc[mi][0][reg] + qv[0]) * vv[0] +
                fast_tanh(acc[mi][1][reg] + qv[1]) * vv[1] +
                fast_tanh(acc[mi][2][reg] + qv[2]) * vv[2] +
                fast_tanh(acc[mi][3][reg] + qv[3]) * vv[3];
      p += __shfl_xor(p, 1, 64);
      p += __shfl_xor(p, 2, 64);
      p += __shfl_xor(p, 4, 64);
      p += __shfl_xor(p, 8, 64);
      if (c16 == 0) {
        int mrow = mb * 256 + wr * 128 + mi * 16 + quad * 4 + reg;
        atomicAdd(&score[mrow], p);
      }
    }
  }
}

// ---------------------------------------------------------------------------
// Kernel B fallback (small ws): fp32-in, cvt per tile (R3 core, fast_tanh).
// ---------------------------------------------------------------------------
__global__ __launch_bounds__(256) void score_gemm_kernel(
    const float* __restrict__ values, const float* __restrict__ W1,
    const float* __restrict__ qpb, const float* __restrict__ V,
    float* __restrict__ score) {
  __shared__ _Float16 aS[4 * 128 * 8];
  __shared__ _Float16 bS[4 * 128 * 8];

  const int tid = threadIdx.x;
  const int mBase = (blockIdx.x >> 3) * 128;
  const int nBase = (blockIdx.x & 7) * 128;

  const int am = tid >> 1;
  const int akh = (tid & 1) * 16;
  const float* aG = values + (size_t)(mBase + am) * DD + akh;
  const int aOff0 = (((tid & 1) * 2) * 128 + am) * 8;
  const int bu2 = (tid & 63) * 2;
  const int bkq = tid >> 6;
  const float* bG = W1 + (size_t)(bkq * 8) * UU + nBase + bu2;
  const int bOff0 = (bkq * 128 + bu2) * 8;

  const int lane = tid & 63;
  const int wave = tid >> 6;
  const int wm = (wave & 1) * 64;
  const int wn = (wave >> 1) * 64;
  const int quad = lane >> 4;
  const int c16 = lane & 15;

  f32x4 acc[4][4];
#pragma unroll
  for (int mi = 0; mi < 4; ++mi)
#pragma unroll
    for (int ni = 0; ni < 4; ++ni) acc[mi][ni] = (f32x4)0.f;

  for (int k0 = 0; k0 < DD; k0 += 32) {
    float4 a0 = *(const float4*)(aG + k0 + 0);
    float4 a1 = *(const float4*)(aG + k0 + 4);
    float4 a2 = *(const float4*)(aG + k0 + 8);
    float4 a3 = *(const float4*)(aG + k0 + 12);
    const float* bRow = bG + (size_t)k0 * UU;
    float2 g0 = *(const float2*)(bRow + 0 * UU);
    float2 g1 = *(const float2*)(bRow + 1 * UU);
    float2 g2 = *(const float2*)(bRow + 2 * UU);
    float2 g3 = *(const float2*)(bRow + 3 * UU);
    float2 g4 = *(const float2*)(bRow + 4 * UU);
    float2 g5 = *(const float2*)(bRow + 5 * UU);
    float2 g6 = *(const float2*)(bRow + 6 * UU);
    float2 g7 = *(const float2*)(bRow + 7 * UU);

    __syncthreads();

    H8 ha0, ha1, hb0, hb1;
    ha0.p[0] = pk(a0.x, a0.y); ha0.p[1] = pk(a0.z, a0.w);
    ha0.p[2] = pk(a1.x, a1.y); ha0.p[3] = pk(a1.z, a1.w);
    ha1.p[0] = pk(a2.x, a2.y); ha1.p[1] = pk(a2.z, a2.w);
    ha1.p[2] = pk(a3.x, a3.y); ha1.p[3] = pk(a3.z, a3.w);
    *(f16x8*)&aS[aOff0] = ha0.v;
    *(f16x8*)&aS[aOff0 + 1024] = ha1.v;

    hb0.p[0] = pk(g0.x, g1.x); hb0.p[1] = pk(g2.x, g3.x);
    hb0.p[2] = pk(g4.x, g5.x); hb0.p[3] = pk(g6.x, g7.x);
    hb1.p[0] = pk(g0.y, g1.y); hb1.p[1] = pk(g2.y, g3.y);
    hb1.p[2] = pk(g4.y, g5.y); hb1.p[3] = pk(g6.y, g7.y);
    *(f16x8*)&bS[bOff0] = hb0.v;
    *(f16x8*)&bS[bOff0 + 8] = hb1.v;

    __syncthreads();

    f16x8 af[4], bf[4];
#pragma unroll
    for (int i = 0; i < 4; ++i) {
      af[i] = *(const f16x8*)&aS[(quad * 128 + wm + i * 16 + c16) * 8];
      bf[i] = *(const f16x8*)&bS[(quad * 128 + wn + i * 16 + c16) * 8];
    }
#pragma unroll
    for (int mi = 0; mi < 4; ++mi)
#pragma unroll
      for (int ni = 0; ni < 4; ++ni)
        acc[mi][ni] = __builtin_amdgcn_mfma_f32_16x16x32_f16(
            af[mi], bf[ni], acc[mi][ni], 0, 0, 0);
  }

  const int b = mBase >> 10;
  float qv[4], vv[4];
#pragma unroll
  for (int ni = 0; ni < 4; ++ni) {
    int ug = nBase + wn + ni * 16 + c16;
    qv[ni] = qpb[b * UU + ug];
    vv[ni] = V[ug];
  }
#pragma unroll
  for (int mi = 0; mi < 4; ++mi) {
#pragma unroll
    for (int reg = 0; reg < 4; ++reg) {
      float p = fast_tanh(acc[mi][0][reg] + qv[0]) * vv[0] +
                fast_tanh(acc[mi][1][reg] + qv[1]) * vv[1] +
                fast_tanh(acc[mi][2][reg] + qv[2]) * vv[2] +
                fast_tanh(acc[mi][3][reg] + qv[3]) * vv[3];
      p += __shfl_xor(p, 1, 64);
      p += __shfl_xor(p, 2, 64);
      p += __shfl_xor(p, 4, 64);
      p += __shfl_xor(p, 8, 64);
      if (c16 == 0) {
        int mrow = mBase + wm + mi * 16 + quad * 4 + reg;
        atomicAdd(&score[mrow], p);
      }
    }
  }
}

// ---------------------------------------------------------------------------
// Kernel C: softmax over T per batch, in-place. 1024 threads, 1 elem each,
// shfl reductions.
// ---------------------------------------------------------------------------
__global__ __launch_bounds__(1024) void softmax_kernel(float* __restrict__ sw) {
  __shared__ float red[16];
  const int b = blockIdx.x;
  const int tid = threadIdx.x;
  const int wid = tid >> 6, lane = tid & 63;
  float* s = sw + b * TS;

  const float v = s[tid];

  float m = v;
#pragma unroll
  for (int off = 32; off > 0; off >>= 1) m = fmaxf(m, __shfl_xor(m, off, 64));
  if (lane == 0) red[wid] = m;
  __syncthreads();
  float mm = red[0];
#pragma unroll
  for (int i = 1; i < 16; ++i) mm = fmaxf(mm, red[i]);
  __syncthreads();

  const float e = expf(v - mm);
  float sum = e;
#pragma unroll
  for (int off = 32; off > 0; off >>= 1) sum += __shfl_xor(sum, off, 64);
  if (lane == 0) red[wid] = sum;
  __syncthreads();
  float tot = 0.f;
#pragma unroll
  for (int i = 0; i < 16; ++i) tot += red[i];

  s[tid] = e * (1.f / tot);
}

// ---------------------------------------------------------------------------
// Kernel D (fp16 image): context[b][d] = sum_t w[b][t] * v[b][t][d].
// Grid 1024 = b(32) x kc(32, 64-d chunks). Block 256 = 4 waves.
// ---------------------------------------------------------------------------
__global__ __launch_bounds__(256) void context_p_kernel(
    const _Float16* __restrict__ vhp, const float* __restrict__ weights,
    float* __restrict__ context) {
  __shared__ float wl[TS];
  const int b = blockIdx.x >> 5;
  const int kc = blockIdx.x & 31;
  const int tid = threadIdx.x;
  const int lane = tid & 63, wave = tid >> 6;

  for (int i = tid; i < TS; i += 256) wl[i] = weights[b * TS + i];
  __syncthreads();

  const int khiA = wave;
  const int khiB = wave + 4;

  float acc0[8], acc1[8];
#pragma unroll
  for (int j = 0; j < 8; ++j) { acc0[j] = 0.f; acc1[j] = 0.f; }

  for (int mt8 = 0; mt8 < 8; ++mt8) {
    const _Float16* base = vhp + ((size_t)(b * 8 + mt8) * 32 + kc) * 8192;
    const float* wrow = &wl[mt8 * 128];
#pragma unroll
    for (int half = 0; half < 2; ++half) {
      const int row = half * 64 + lane;
      const float wt = wrow[row];
      f16x8 vA = *(const f16x8*)&base[(khiA * 128 + row) * 8];
      f16x8 vB = *(const f16x8*)&base[(khiB * 128 + row) * 8];
#pragma unroll
      for (int j = 0; j < 8; ++j) {
        acc0[j] += wt * (float)vA[j];
        acc1[j] += wt * (float)vB[j];
      }
    }
  }

#pragma unroll
  for (int j = 0; j < 8; ++j) {
    float a = acc0[j], c = acc1[j];
#pragma unroll
    for (int off = 1; off < 64; off <<= 1) {
      a += __shfl_xor(a, off, 64);
      c += __shfl_xor(c, off, 64);
    }
    acc0[j] = a; acc1[j] = c;
  }

  if (lane == 0) {
    float* dst = context + b * DD + kc * 64;
#pragma unroll
    for (int j = 0; j < 8; ++j) {
      dst[khiA * 8 + j] = acc0[j];
      dst[khiB * 8 + j] = acc1[j];
    }
  }
}

// ---------------------------------------------------------------------------
// Kernel D fallback (small ws): fp32 values read.
// ---------------------------------------------------------------------------
__global__ __launch_bounds__(1024) void context_kernel(
    const float* __restrict__ values, const float* __restrict__ weights,
    float* __restrict__ context) {
  __shared__ float wl[TS];
  __shared__ float4 part[15][64];
  const int b = blockIdx.x >> 3;
  const int d0 = (blockIdx.x & 7) * 256;
  const int tid = threadIdx.x;
  const int slice = tid >> 6, dl = tid & 63;

  wl[tid] = weights[b * TS + tid];
  __syncthreads();

  const float* vb = values + ((size_t)b * TS + slice * 64) * DD + d0 + dl * 4;
  float4 acc = {0.f, 0.f, 0.f, 0.f};
#pragma unroll 8
  for (int t = 0; t < 64; ++t) {
    float w = wl[slice * 64 + t];
    float4 v4 = *(const float4*)(vb + (size_t)t * DD);
    acc.x += w * v4.x; acc.y += w * v4.y;
    acc.z += w * v4.z; acc.w += w * v4.w;
  }

  if (slice) part[slice - 1][dl] = acc;
  __syncthreads();
  if (slice == 0) {
#pragma unroll
    for (int i = 0; i < 15; ++i) {
      float4 p = part[i][dl];
      acc.x += p.x; acc.y += p.y; acc.z += p.z; acc.w += p.w;
    }
    *(float4*)(context + b * DD + d0 + dl * 4) = acc;
  }
}

// ---------------------------------------------------------------------------
extern "C" void kernel_launch(void* const* d_in, const int* in_sizes, int n_in,
                              void* d_out, int out_size, void* d_ws, size_t ws_size,
                              hipStream_t stream) {
  const float* query  = (const float*)d_in[0];
  const float* values = (const float*)d_in[1];
  const float* W1     = (const float*)d_in[2];
  const float* b1     = (const float*)d_in[3];
  const float* W2     = (const float*)d_in[4];
  const float* b2     = (const float*)d_in[5];
  const float* V      = (const float*)d_in[6];
  // d_in[7] = bv cancels in softmax; unused.

  float* out = (float*)d_out;
  float* context = out;            // B*D (output 0)
  float* weights = out + BB * DD;  // B*T (output 1)

  float* qpb   = context;  // atomic target; overwritten by context kernel later
  float* score = weights;  // atomic target; softmax in-place

  const size_t need = (size_t)BB * TS * DD * 2 + (size_t)DD * UU * 2;
  const bool big_ws = ws_size >= need;

  zero_kernel<<<96, 1024, 0, stream>>>(out);  // zeros qpb + score regions
  qproj_kernel<<<128, 256, 0, stream>>>(query, W2, b1, b2, qpb);

  if (big_ws) {
    _Float16* vhp = (_Float16*)d_ws;
    _Float16* w1p = vhp + (size_t)BB * TS * DD;
    pack_values_kernel<<<256 * 32, 256, 0, stream>>>(values, vhp);
    pack_w1_kernel<<<8 * 32, 256, 0, stream>>>(W1, w1p);
    score_gemm_p4_kernel<<<(BB * TS / 256) * (UU / 256), 512, 0, stream>>>(
        vhp, w1p, qpb, V, score);
    softmax_kernel<<<BB, 1024, 0, stream>>>(score);
    context_p_kernel<<<BB * 32, 256, 0, stream>>>(vhp, weights, context);
  } else {
    score_gemm_kernel<<<(BB * TS / 128) * (UU / 128), 256, 0, stream>>>(
        values, W1, qpb, V, score);
    softmax_kernel<<<BB, 1024, 0, stream>>>(score);
    context_kernel<<<BB * 8, 1024, 0, stream>>>(values, weights, context);
  }
}

// Round 9
// 574.103 us; speedup vs baseline: 1.0355x; 1.0343x over previous
//
#include <hip/hip_runtime.h>
#include <math.h>

#define BB 32
#define TS 1024
#define DD 2048
#define UU 1024

typedef _Float16 f16x8 __attribute__((ext_vector_type(8)));
typedef _Float16 f16x2 __attribute__((ext_vector_type(2)));
typedef __fp16 fp16x2 __attribute__((ext_vector_type(2)));
typedef float f32x4 __attribute__((ext_vector_type(4)));

union H8 { f16x8 v; f16x2 p[4]; };

static __device__ inline f16x2 pk(float a, float b) {
  fp16x2 r = __builtin_amdgcn_cvt_pkrtz(a, b);
  return __builtin_bit_cast(f16x2, r);
}

// tanh via hw exp2+rcp: exact at +-inf, ~1e-6 abs err, ~5 VALU ops
static __device__ inline float fast_tanh(float x) {
  float e = __builtin_amdgcn_exp2f(x * 2.885390081777927f);  // exp(2x)
  return 1.f - 2.f * __builtin_amdgcn_rcpf(1.f + e);
}

// async global->LDS, 16B/lane; LDS dest wave-uniform (HW adds lane*16).
static __device__ inline void gld16(const _Float16* g, _Float16* l) {
  __builtin_amdgcn_global_load_lds(
      (const __attribute__((address_space(1))) void*)g,
      (__attribute__((address_space(3))) void*)l, 16, 0, 0);
}

// ---------------------------------------------------------------------------
// zero all of d_out (qpb lives in context region, score in weights region;
// both are atomic targets). 96 blocks x 1024 = 98304 floats.
// ---------------------------------------------------------------------------
__global__ void zero_kernel(float* __restrict__ p) {
  p[blockIdx.x * 1024 + threadIdx.x] = 0.f;
}

// ---------------------------------------------------------------------------
// Kernel A: qpb[b][u] += partial of query@W2 (+b1+b2 once).
// Grid 128 = (u0 in 8 x 128u) x (dsl in 16 x 128d). W2 read exactly once.
// ---------------------------------------------------------------------------
__global__ __launch_bounds__(256) void qproj_kernel(
    const float* __restrict__ query, const float* __restrict__ W2,
    const float* __restrict__ b1, const float* __restrict__ b2,
    float* __restrict__ qpb) {
  __shared__ float qs[32][128];  // 16 KB
  const int u0 = (blockIdx.x & 7) * 128;
  const int dsl = blockIdx.x >> 3;   // 0..15
  const int d0 = dsl * 128;
  const int tid = threadIdx.x;
  const int ul = tid & 127, half = tid >> 7;

  for (int i = tid; i < 32 * 32; i += 256) {  // 1024 float4 = 16 KB
    int b = i >> 5, dq = i & 31;
    *(float4*)&qs[b][dq * 4] = *(const float4*)(query + b * DD + d0 + dq * 4);
  }
  __syncthreads();

  float acc[32];
#pragma unroll
  for (int b = 0; b < 32; ++b) acc[b] = 0.f;

  const float* wcol = W2 + (size_t)(d0 + half * 64) * UU + u0 + ul;
  for (int dd = 0; dd < 64; dd += 4) {
    float w0 = wcol[(size_t)(dd + 0) * UU];
    float w1 = wcol[(size_t)(dd + 1) * UU];
    float w2 = wcol[(size_t)(dd + 2) * UU];
    float w3 = wcol[(size_t)(dd + 3) * UU];
#pragma unroll
    for (int b = 0; b < 32; ++b) {
      float4 q4 = *(const float4*)&qs[b][half * 64 + dd];
      acc[b] += q4.x * w0 + q4.y * w1 + q4.z * w2 + q4.w * w3;
    }
  }

  const int u = u0 + ul;
  const float bias = (dsl == 0 && half == 0) ? (b1[u] + b2[u]) : 0.f;
#pragma unroll
  for (int b = 0; b < 32; ++b) atomicAdd(&qpb[b * UU + u], acc[b] + bias);
}

// ---------------------------------------------------------------------------
// Pre-pass 1: values fp32 -> packed fp16 MFMA image (proven in R5).
// Output image is LINEAR: vhp[((mt*32+kc)*1024 + khi*128 + row)*8 + klo]
//   = fp16(values[mt*128+row][kc*64 + khi*8 + klo]).
// Note: for fixed mt, offset is linear in 32k-tiles: tile t (k=t*32) starts
// at elem t*4096 — used by the BK=32 GEMM staging.
// ---------------------------------------------------------------------------
__global__ __launch_bounds__(256) void pack_values_kernel(
    const float* __restrict__ v, _Float16* __restrict__ vhp) {
  __shared__ _Float16 img[8192];  // 16 KB
  const int mTile = blockIdx.x >> 5;
  const int kc = blockIdx.x & 31;
  const int tid = threadIdx.x;

#pragma unroll
  for (int i = 0; i < 4; ++i) {
    int idx = i * 256 + tid;
    int row = idx >> 3, khi = idx & 7;
    const float* src = v + ((size_t)(mTile * 128 + row)) * DD + kc * 64 + khi * 8;
    float4 x = *(const float4*)src;
    float4 y = *(const float4*)(src + 4);
    H8 h;
    h.p[0] = pk(x.x, x.y); h.p[1] = pk(x.z, x.w);
    h.p[2] = pk(y.x, y.y); h.p[3] = pk(y.z, y.w);
    *(f16x8*)&img[(khi * 128 + (row ^ khi)) * 8] = h.v;
  }
  __syncthreads();

  _Float16* out = vhp + ((size_t)mTile * 32 + kc) * 8192;
#pragma unroll
  for (int i = 0; i < 4; ++i) {
    int p = i * 256 + tid;
    int khi = p >> 7, row = p & 127;
    *(f16x8*)(out + (size_t)p * 8) = *(const f16x8*)&img[(khi * 128 + (row ^ khi)) * 8];
  }
}

// ---------------------------------------------------------------------------
// Pre-pass 2: W1 -> packed fp16 image of W1^T (proven in R5).
// ---------------------------------------------------------------------------
__global__ __launch_bounds__(256) void pack_w1_kernel(
    const float* __restrict__ W1, _Float16* __restrict__ w1p) {
  __shared__ _Float16 img[8192];
  const int nTile = blockIdx.x >> 5;
  const int kc = blockIdx.x & 31;
  const int tid = threadIdx.x;

#pragma unroll
  for (int i = 0; i < 32; ++i) {
    int idx = i * 256 + tid;
    int ul = idx & 127, kl = idx >> 7;
    float x = W1[(size_t)(kc * 64 + kl) * UU + nTile * 128 + ul];
    int khi = kl >> 3, klo = kl & 7;
    img[(khi * 128 + (ul ^ khi)) * 8 + klo] = (_Float16)x;
  }
  __syncthreads();

  _Float16* out = w1p + ((size_t)nTile * 32 + kc) * 8192;
#pragma unroll
  for (int i = 0; i < 4; ++i) {
    int p = i * 256 + tid;
    int khi = p >> 7, row = p & 127;
    *(f16x8*)(out + (size_t)p * 8) = *(const f16x8*)&img[(khi * 128 + (row ^ khi)) * 8];
  }
}

// ---------------------------------------------------------------------------
// Kernel B (R8): 256x256 tile, BK=32, 64 K-tiles, 4 LDS slots (128 KB),
// ONE barrier + one counted vmcnt(4) per K-tile. Stage tile t+3 during t.
// No intra-tile barriers/fences: the 12 ds_read_b128 + 32 MFMA + 4 gld16 per
// wave are left to the compiler to interleave (counted lgkmcnt), so the LDS
// pipe and MFMA pipe overlap instead of strictly alternating (R5/R6/R7 all
// serialized them; MFMA 58us + LDS ~82us back-to-back == the measured 167).
// Ledger: at t-end in-flight = {STAGE(t+2), STAGE(t+3)}; vmcnt(4) drains
// t+2's (one tile early); t+1's drained at t-1's end. WAR: slot (t+3)%4
// last read at t-1; t's stages issue after t-1's end barrier.
// ---------------------------------------------------------------------------
__global__ __launch_bounds__(512, 2) void score_gemm_p5_kernel(
    const _Float16* __restrict__ vhp, const _Float16* __restrict__ w1p,
    const float* __restrict__ qpb, const float* __restrict__ V,
    float* __restrict__ score) {
  __shared__ _Float16 aS[4][8192];  // 4 slots x [mhalf2][khi4][row128][klo8] = 64 KB
  __shared__ _Float16 bS[4][8192];  // 64 KB

  const int tid = threadIdx.x;
  const int lane = tid & 63, wave = tid >> 6;

  // XCD-aware swizzle (512 blocks = 8 XCDs x 64, bijective); the 4 nb-blocks
  // of each mb land on one XCD -> A panel served from that XCD's L2.
  const int swz = (blockIdx.x & 7) * 64 + (blockIdx.x >> 3);
  const int mb = swz >> 2;   // 0..127 (256-row M tile)
  const int nb = swz & 3;    // 0..3   (256-col N tile)

  const int wr = wave >> 2;  // 0..1: M half (128 rows)
  const int wc = wave & 3;   // 0..3: N quarter (64 cols)
  const int quad = lane >> 4, c16 = lane & 15;

  // image streams: tile t (k = t*32) = 4096 elems per 128-row/col subtile
  const _Float16* gA0 = vhp + ((size_t)(2 * mb + 0) * 32) * 8192 + lane * 8;
  const _Float16* gA1 = vhp + ((size_t)(2 * mb + 1) * 32) * 8192 + lane * 8;
  const _Float16* gB0 = w1p + ((size_t)(2 * nb + 0) * 32) * 8192 + lane * 8;
  const _Float16* gB1 = w1p + ((size_t)(2 * nb + 1) * 32) * 8192 + lane * 8;

  f32x4 acc[8][4];
#pragma unroll
  for (int mi = 0; mi < 8; ++mi)
#pragma unroll
    for (int ni = 0; ni < 4; ++ni) acc[mi][ni] = (f32x4)0.f;

  // stage one 32-KB K-tile (A 16KB + B 16KB): 4 gld16/wave
  auto STAGE = [&](int kt, int sl) {
    gld16(gA0 + (size_t)kt * 4096 + wave * 512, &aS[sl][0 * 4096 + wave * 512]);
    gld16(gA1 + (size_t)kt * 4096 + wave * 512, &aS[sl][1 * 4096 + wave * 512]);
    gld16(gB0 + (size_t)kt * 4096 + wave * 512, &bS[sl][0 * 4096 + wave * 512]);
    gld16(gB1 + (size_t)kt * 4096 + wave * 512, &bS[sl][1 * 4096 + wave * 512]);
  };

  // epilogue params FIRST so their vmem loads are oldest (drained at first wait)
  const int b = mb >> 2;
  const int nBase = nb * 256;
  float qv[4], vv[4];
#pragma unroll
  for (int ni = 0; ni < 4; ++ni) {
    int ug = nBase + wc * 64 + ni * 16 + c16;
    qv[ni] = qpb[b * UU + ug];
    vv[ni] = V[ug];
  }

  // prologue: pre-stage tiles 0,1,2 into slots 0,1,2; wait for tile 0.
  // vmcnt(8): of the 20 outstanding (8 qv/vv + 12 stage), any oldest-12
  // drain leaves tile 0 landed regardless of compiler issue interleave.
  STAGE(0, 0); STAGE(1, 1); STAGE(2, 2);
  asm volatile("s_waitcnt vmcnt(8)" ::: "memory");
  __builtin_amdgcn_s_barrier();

  const int aBase = wr * 4096 + quad * 1024 + c16 * 8;
  const int bBase = (wc >> 1) * 4096 + quad * 1024 + ((wc & 1) * 64 + c16) * 8;

#pragma unroll 4
  for (int t = 0; t < 64; ++t) {
    const int sl = t & 3;
    if (t < 61) STAGE(t + 3, (t + 3) & 3);

    f16x8 bf[4];
#pragma unroll
    for (int ni = 0; ni < 4; ++ni)
      bf[ni] = *(const f16x8*)&bS[sl][bBase + ni * 128];

    __builtin_amdgcn_s_setprio(1);
#pragma unroll
    for (int g = 0; g < 2; ++g) {
      f16x8 af[4];
#pragma unroll
      for (int mi = 0; mi < 4; ++mi)
        af[mi] = *(const f16x8*)&aS[sl][aBase + (g * 4 + mi) * 128];
#pragma unroll
      for (int mi = 0; mi < 4; ++mi)
#pragma unroll
        for (int ni = 0; ni < 4; ++ni)
          acc[g * 4 + mi][ni] = __builtin_amdgcn_mfma_f32_16x16x32_f16(
              af[mi], bf[ni], acc[g * 4 + mi][ni], 0, 0, 0);
    }
    __builtin_amdgcn_s_setprio(0);

    if (t < 63) {
      if (t < 61) {
        asm volatile("s_waitcnt vmcnt(4)" ::: "memory");
      } else {
        asm volatile("s_waitcnt vmcnt(0)" ::: "memory");
      }
      __builtin_amdgcn_s_barrier();
    }
  }

#pragma unroll
  for (int mi = 0; mi < 8; ++mi) {
#pragma unroll
    for (int reg = 0; reg < 4; ++reg) {
      float p = fast_tanh(acc[mi][0][reg] + qv[0]) * vv[0] +
                fast_tanh(acc[mi][1][reg] + qv[1]) * vv[1] +
                fast_tanh(acc[mi][2][reg] + qv[2]) * vv[2] +
                fast_tanh(acc[mi][3][reg] + qv[3]) * vv[3];
      p += __shfl_xor(p, 1, 64);
      p += __shfl_xor(p, 2, 64);
      p += __shfl_xor(p, 4, 64);
      p += __shfl_xor(p, 8, 64);
      if (c16 == 0) {
        int mrow = mb * 256 + wr * 128 + mi * 16 + quad * 4 + reg;
        atomicAdd(&score[mrow], p);
      }
    }
  }
}

// ---------------------------------------------------------------------------
// Kernel B fallback (small ws): fp32-in, cvt per tile (R3 core, fast_tanh).
// ---------------------------------------------------------------------------
__global__ __launch_bounds__(256) void score_gemm_kernel(
    const float* __restrict__ values, const float* __restrict__ W1,
    const float* __restrict__ qpb, const float* __restrict__ V,
    float* __restrict__ score) {
  __shared__ _Float16 aS[4 * 128 * 8];
  __shared__ _Float16 bS[4 * 128 * 8];

  const int tid = threadIdx.x;
  const int mBase = (blockIdx.x >> 3) * 128;
  const int nBase = (blockIdx.x & 7) * 128;

  const int am = tid >> 1;
  const int akh = (tid & 1) * 16;
  const float* aG = values + (size_t)(mBase + am) * DD + akh;
  const int aOff0 = (((tid & 1) * 2) * 128 + am) * 8;
  const int bu2 = (tid & 63) * 2;
  const int bkq = tid >> 6;
  const float* bG = W1 + (size_t)(bkq * 8) * UU + nBase + bu2;
  const int bOff0 = (bkq * 128 + bu2) * 8;

  const int lane = tid & 63;
  const int wave = tid >> 6;
  const int wm = (wave & 1) * 64;
  const int wn = (wave >> 1) * 64;
  const int quad = lane >> 4;
  const int c16 = lane & 15;

  f32x4 acc[4][4];
#pragma unroll
  for (int mi = 0; mi < 4; ++mi)
#pragma unroll
    for (int ni = 0; ni < 4; ++ni) acc[mi][ni] = (f32x4)0.f;

  for (int k0 = 0; k0 < DD; k0 += 32) {
    float4 a0 = *(const float4*)(aG + k0 + 0);
    float4 a1 = *(const float4*)(aG + k0 + 4);
    float4 a2 = *(const float4*)(aG + k0 + 8);
    float4 a3 = *(const float4*)(aG + k0 + 12);
    const float* bRow = bG + (size_t)k0 * UU;
    float2 g0 = *(const float2*)(bRow + 0 * UU);
    float2 g1 = *(const float2*)(bRow + 1 * UU);
    float2 g2 = *(const float2*)(bRow + 2 * UU);
    float2 g3 = *(const float2*)(bRow + 3 * UU);
    float2 g4 = *(const float2*)(bRow + 4 * UU);
    float2 g5 = *(const float2*)(bRow + 5 * UU);
    float2 g6 = *(const float2*)(bRow + 6 * UU);
    float2 g7 = *(const float2*)(bRow + 7 * UU);

    __syncthreads();

    H8 ha0, ha1, hb0, hb1;
    ha0.p[0] = pk(a0.x, a0.y); ha0.p[1] = pk(a0.z, a0.w);
    ha0.p[2] = pk(a1.x, a1.y); ha0.p[3] = pk(a1.z, a1.w);
    ha1.p[0] = pk(a2.x, a2.y); ha1.p[1] = pk(a2.z, a2.w);
    ha1.p[2] = pk(a3.x, a3.y); ha1.p[3] = pk(a3.z, a3.w);
    *(f16x8*)&aS[aOff0] = ha0.v;
    *(f16x8*)&aS[aOff0 + 1024] = ha1.v;

    hb0.p[0] = pk(g0.x, g1.x); hb0.p[1] = pk(g2.x, g3.x);
    hb0.p[2] = pk(g4.x, g5.x); hb0.p[3] = pk(g6.x, g7.x);
    hb1.p[0] = pk(g0.y, g1.y); hb1.p[1] = pk(g2.y, g3.y);
    hb1.p[2] = pk(g4.y, g5.y); hb1.p[3] = pk(g6.y, g7.y);
    *(f16x8*)&bS[bOff0] = hb0.v;
    *(f16x8*)&bS[bOff0 + 8] = hb1.v;

    __syncthreads();

    f16x8 af[4], bf[4];
#pragma unroll
    for (int i = 0; i < 4; ++i) {
      af[i] = *(const f16x8*)&aS[(quad * 128 + wm + i * 16 + c16) * 8];
      bf[i] = *(const f16x8*)&bS[(quad * 128 + wn + i * 16 + c16) * 8];
    }
#pragma unroll
    for (int mi = 0; mi < 4; ++mi)
#pragma unroll
      for (int ni = 0; ni < 4; ++ni)
        acc[mi][ni] = __builtin_amdgcn_mfma_f32_16x16x32_f16(
            af[mi], bf[ni], acc[mi][ni], 0, 0, 0);
  }

  const int b = mBase >> 10;
  float qv[4], vv[4];
#pragma unroll
  for (int ni = 0; ni < 4; ++ni) {
    int ug = nBase + wn + ni * 16 + c16;
    qv[ni] = qpb[b * UU + ug];
    vv[ni] = V[ug];
  }
#pragma unroll
  for (int mi = 0; mi < 4; ++mi) {
#pragma unroll
    for (int reg = 0; reg < 4; ++reg) {
      float p = fast_tanh(acc[mi][0][reg] + qv[0]) * vv[0] +
                fast_tanh(acc[mi][1][reg] + qv[1]) * vv[1] +
                fast_tanh(acc[mi][2][reg] + qv[2]) * vv[2] +
                fast_tanh(acc[mi][3][reg] + qv[3]) * vv[3];
      p += __shfl_xor(p, 1, 64);
      p += __shfl_xor(p, 2, 64);
      p += __shfl_xor(p, 4, 64);
      p += __shfl_xor(p, 8, 64);
      if (c16 == 0) {
        int mrow = mBase + wm + mi * 16 + quad * 4 + reg;
        atomicAdd(&score[mrow], p);
      }
    }
  }
}

// ---------------------------------------------------------------------------
// Kernel C: softmax over T per batch, in-place. 1024 threads, 1 elem each,
// shfl reductions.
// ---------------------------------------------------------------------------
__global__ __launch_bounds__(1024) void softmax_kernel(float* __restrict__ sw) {
  __shared__ float red[16];
  const int b = blockIdx.x;
  const int tid = threadIdx.x;
  const int wid = tid >> 6, lane = tid & 63;
  float* s = sw + b * TS;

  const float v = s[tid];

  float m = v;
#pragma unroll
  for (int off = 32; off > 0; off >>= 1) m = fmaxf(m, __shfl_xor(m, off, 64));
  if (lane == 0) red[wid] = m;
  __syncthreads();
  float mm = red[0];
#pragma unroll
  for (int i = 1; i < 16; ++i) mm = fmaxf(mm, red[i]);
  __syncthreads();

  const float e = expf(v - mm);
  float sum = e;
#pragma unroll
  for (int off = 32; off > 0; off >>= 1) sum += __shfl_xor(sum, off, 64);
  if (lane == 0) red[wid] = sum;
  __syncthreads();
  float tot = 0.f;
#pragma unroll
  for (int i = 0; i < 16; ++i) tot += red[i];

  s[tid] = e * (1.f / tot);
}

// ---------------------------------------------------------------------------
// Kernel D (fp16 image): context[b][d] = sum_t w[b][t] * v[b][t][d].
// Grid 1024 = b(32) x kc(32, 64-d chunks). Block 256 = 4 waves.
// ---------------------------------------------------------------------------
__global__ __launch_bounds__(256) void context_p_kernel(
    const _Float16* __restrict__ vhp, const float* __restrict__ weights,
    float* __restrict__ context) {
  __shared__ float wl[TS];
  const int b = blockIdx.x >> 5;
  const int kc = blockIdx.x & 31;
  const int tid = threadIdx.x;
  const int lane = tid & 63, wave = tid >> 6;

  for (int i = tid; i < TS; i += 256) wl[i] = weights[b * TS + i];
  __syncthreads();

  const int khiA = wave;
  const int khiB = wave + 4;

  float acc0[8], acc1[8];
#pragma unroll
  for (int j = 0; j < 8; ++j) { acc0[j] = 0.f; acc1[j] = 0.f; }

  for (int mt8 = 0; mt8 < 8; ++mt8) {
    const _Float16* base = vhp + ((size_t)(b * 8 + mt8) * 32 + kc) * 8192;
    const float* wrow = &wl[mt8 * 128];
#pragma unroll
    for (int half = 0; half < 2; ++half) {
      const int row = half * 64 + lane;
      const float wt = wrow[row];
      f16x8 vA = *(const f16x8*)&base[(khiA * 128 + row) * 8];
      f16x8 vB = *(const f16x8*)&base[(khiB * 128 + row) * 8];
#pragma unroll
      for (int j = 0; j < 8; ++j) {
        acc0[j] += wt * (float)vA[j];
        acc1[j] += wt * (float)vB[j];
      }
    }
  }

#pragma unroll
  for (int j = 0; j < 8; ++j) {
    float a = acc0[j], c = acc1[j];
#pragma unroll
    for (int off = 1; off < 64; off <<= 1) {
      a += __shfl_xor(a, off, 64);
      c += __shfl_xor(c, off, 64);
    }
    acc0[j] = a; acc1[j] = c;
  }

  if (lane == 0) {
    float* dst = context + b * DD + kc * 64;
#pragma unroll
    for (int j = 0; j < 8; ++j) {
      dst[khiA * 8 + j] = acc0[j];
      dst[khiB * 8 + j] = acc1[j];
    }
  }
}

// ---------------------------------------------------------------------------
// Kernel D fallback (small ws): fp32 values read.
// ---------------------------------------------------------------------------
__global__ __launch_bounds__(1024) void context_kernel(
    const float* __restrict__ values, const float* __restrict__ weights,
    float* __restrict__ context) {
  __shared__ float wl[TS];
  __shared__ float4 part[15][64];
  const int b = blockIdx.x >> 3;
  const int d0 = (blockIdx.x & 7) * 256;
  const int tid = threadIdx.x;
  const int slice = tid >> 6, dl = tid & 63;

  wl[tid] = weights[b * TS + tid];
  __syncthreads();

  const float* vb = values + ((size_t)b * TS + slice * 64) * DD + d0 + dl * 4;
  float4 acc = {0.f, 0.f, 0.f, 0.f};
#pragma unroll 8
  for (int t = 0; t < 64; ++t) {
    float w = wl[slice * 64 + t];
    float4 v4 = *(const float4*)(vb + (size_t)t * DD);
    acc.x += w * v4.x; acc.y += w * v4.y;
    acc.z += w * v4.z; acc.w += w * v4.w;
  }

  if (slice) part[slice - 1][dl] = acc;
  __syncthreads();
  if (slice == 0) {
#pragma unroll
    for (int i = 0; i < 15; ++i) {
      float4 p = part[i][dl];
      acc.x += p.x; acc.y += p.y; acc.z += p.z; acc.w += p.w;
    }
    *(float4*)(context + b * DD + d0 + dl * 4) = acc;
  }
}

// ---------------------------------------------------------------------------
extern "C" void kernel_launch(void* const* d_in, const int* in_sizes, int n_in,
                              void* d_out, int out_size, void* d_ws, size_t ws_size,
                              hipStream_t stream) {
  const float* query  = (const float*)d_in[0];
  const float* values = (const float*)d_in[1];
  const float* W1     = (const float*)d_in[2];
  const float* b1     = (const float*)d_in[3];
  const float* W2     = (const float*)d_in[4];
  const float* b2     = (const float*)d_in[5];
  const float* V      = (const float*)d_in[6];
  // d_in[7] = bv cancels in softmax; unused.

  float* out = (float*)d_out;
  float* context = out;            // B*D (output 0)
  float* weights = out + BB * DD;  // B*T (output 1)

  float* qpb   = context;  // atomic target; overwritten by context kernel later
  float* score = weights;  // atomic target; softmax in-place

  const size_t need = (size_t)BB * TS * DD * 2 + (size_t)DD * UU * 2;
  const bool big_ws = ws_size >= need;

  zero_kernel<<<96, 1024, 0, stream>>>(out);  // zeros qpb + score regions
  qproj_kernel<<<128, 256, 0, stream>>>(query, W2, b1, b2, qpb);

  if (big_ws) {
    _Float16* vhp = (_Float16*)d_ws;
    _Float16* w1p = vhp + (size_t)BB * TS * DD;
    pack_values_kernel<<<256 * 32, 256, 0, stream>>>(values, vhp);
    pack_w1_kernel<<<8 * 32, 256, 0, stream>>>(W1, w1p);
    score_gemm_p5_kernel<<<(BB * TS / 256) * (UU / 256), 512, 0, stream>>>(
        vhp, w1p, qpb, V, score);
    softmax_kernel<<<BB, 1024, 0, stream>>>(score);
    context_p_kernel<<<BB * 32, 256, 0, stream>>>(vhp, weights, context);
  } else {
    score_gemm_kernel<<<(BB * TS / 128) * (UU / 128), 256, 0, stream>>>(
        values, W1, qpb, V, score);
    softmax_kernel<<<BB, 1024, 0, stream>>>(score);
    context_kernel<<<BB * 8, 1024, 0, stream>>>(values, weights, context);
  }
}